// Round 11
// baseline (577.460 us; speedup 1.0000x reference)
//
#include <hip/hip_runtime.h>
#include <cmath>

// Multi-scale residual VQ, round 11.
// R10 lessons: (a) LDS-staged E turned argbig DS-pipe-bound (worse than K$
// path) -> revert to scalar-E loop, add NP=4 points/thread at pn16 to halve
// K$ demand per FMA-cycle. (b) fuse_k's s_pw[(col*CC+ci)*9] puts all 8 col
// groups in ONE bank (col*288%32==0): 8-way conflict on every weight read
// (3.35M conflict cycles measured) -> transpose to [ci*9+tap][col].

#define BB 64
#define CC 32
#define HH 16
#define VV 4096
#define NTOT (BB*CC*HH*HH)   // 524288

__device__ __forceinline__ double cubicw(double x) {
    x = fabs(x);
    const double a = -0.75;
    if (x <= 1.0) return ((a + 2.0) * x - (a + 3.0)) * x * x + 1.0;
    if (x < 2.0)  return (((a * x - 5.0 * a) * x + 8.0 * a) * x - 4.0 * a);
    return 0.0;
}

// monotone float->uint map: d1<d2 (finite) => ordf(d1)<ordf(d2)
__device__ __forceinline__ unsigned int ordf(float d) {
    unsigned int b = __float_as_uint(d);
    return (b & 0x80000000u) ? ~b : (b | 0x80000000u);
}

// init: f_rest=f, f_hat=0, e2 rows, and z for scale 0 (pn=1: per-(b,c) mean).
__global__ void init_k(const float* __restrict__ f, const float* __restrict__ E,
                       float* __restrict__ f_rest, float* __restrict__ f_hat,
                       float* __restrict__ e2, float* __restrict__ z) {
    int i = blockIdx.x * 256 + threadIdx.x;
    if (i < NTOT) { f_rest[i] = f[i]; f_hat[i] = 0.f; }
    if (i < VV) {
        float s = 0.f;
        #pragma unroll
        for (int c = 0; c < CC; ++c) { float e = E[i * CC + c]; s += e * e; }
        e2[i] = s;
    }
    if (i < BB * CC) {   // z0[b*32+c] = mean over 256 pixels (same sum order as down_k)
        const float* src = f + (size_t)i * (HH * HH);
        float s = 0.f;
        for (int j = 0; j < HH * HH; ++j) s += src[j];
        z[i] = s * (1.0f / 256.0f);
    }
}

// Small scales: grid (pn*pn, grp); block = 4 waves; each wave = same 64 points
// (one per lane), wave-specific code range (wave-uniform => scalar E loads).
// Keys stored [m][G].
__global__ __launch_bounds__(256, 4) void argsmall_k(const float* __restrict__ z,
        const float* __restrict__ E, const float* __restrict__ e2,
        unsigned long long* __restrict__ bestk, int M, int G, int gsz) {
    const int t = threadIdx.x;
    int m = blockIdx.x * 64 + (t & 63);
    int w = __builtin_amdgcn_readfirstlane(t >> 6);      // wave id, SGPR
    int wg = blockIdx.y * 4 + w;
    int v0 = wg * gsz;                                    // scalar
    float zr[CC]; float z2 = 0.f;
    const float4* zp = (const float4*)(z + (size_t)m * CC);
    #pragma unroll
    for (int c4 = 0; c4 < 8; ++c4) {
        float4 v = zp[c4];
        zr[c4*4+0] = v.x; zr[c4*4+1] = v.y; zr[c4*4+2] = v.z; zr[c4*4+3] = v.w;
        z2 += v.x*v.x + v.y*v.y + v.z*v.z + v.w*v.w;
    }
    const float* e = E + (size_t)v0 * CC;
    float best = 3.4e38f; int bv = v0;
    for (int v = v0; v < v0 + gsz; v += 2, e += 2 * CC) {
        float a0 = 0.f, a1 = 0.f, b0 = 0.f, b1 = 0.f;
        #pragma unroll
        for (int c = 0; c < CC; c += 2) {
            a0 = fmaf(zr[c],   e[c],      a0);
            a1 = fmaf(zr[c+1], e[c+1],    a1);
            b0 = fmaf(zr[c],   e[CC+c],   b0);
            b1 = fmaf(zr[c+1], e[CC+c+1], b1);
        }
        float dA = fmaf(-2.f, a0 + a1, z2 + e2[v]);
        float dB = fmaf(-2.f, b0 + b1, z2 + e2[v+1]);
        if (dA < best) { best = dA; bv = v; }
        if (dB < best) { best = dB; bv = v + 1; }
    }
    bestk[(size_t)m * G + wg] = ((unsigned long long)ordf(best) << 32) |
                                (unsigned long long)(unsigned int)bv;
}

// Large scales: NP points/thread from precomputed z rows, wave-uniform
// scalar-path E scan (K$). Keys stored [m][G].
template<int NP, int MINW>
__global__ __launch_bounds__(256, MINW) void argbig_k(const float* __restrict__ z,
        const float* __restrict__ E, const float* __restrict__ e2,
        unsigned long long* __restrict__ bestk, int M, int G, int gsz) {
    const int T = gridDim.x * 256;
    const int g = blockIdx.y;
    int   mm[NP];
    bool  act[NP];
    float zr[NP][CC];
    float z2[NP];
    #pragma unroll
    for (int pt = 0; pt < NP; ++pt) {
        int m0 = blockIdx.x * 256 + threadIdx.x + pt * T;
        act[pt] = (m0 < M);
        int m = act[pt] ? m0 : M - 1;
        mm[pt] = m;
        const float4* zp = (const float4*)(z + (size_t)m * CC);
        float zz = 0.f;
        #pragma unroll
        for (int c4 = 0; c4 < 8; ++c4) {
            float4 v = zp[c4];
            zr[pt][c4*4+0] = v.x; zr[pt][c4*4+1] = v.y;
            zr[pt][c4*4+2] = v.z; zr[pt][c4*4+3] = v.w;
            zz += v.x*v.x + v.y*v.y + v.z*v.z + v.w*v.w;
        }
        z2[pt] = zz;
    }
    int v0 = g * gsz;
    const float* e = E + (size_t)v0 * CC;
    float best[NP]; int bv[NP];
    #pragma unroll
    for (int pt = 0; pt < NP; ++pt) { best[pt] = 3.4e38f; bv[pt] = v0; }
    for (int v = v0; v < v0 + gsz; v += 2, e += 2 * CC) {
        float a[NP], b[NP];
        #pragma unroll
        for (int pt = 0; pt < NP; ++pt) { a[pt] = 0.f; b[pt] = 0.f; }
        #pragma unroll
        for (int c = 0; c < CC; ++c) {
            float eA = e[c], eB = e[CC + c];
            #pragma unroll
            for (int pt = 0; pt < NP; ++pt) {
                a[pt] = fmaf(zr[pt][c], eA, a[pt]);
                b[pt] = fmaf(zr[pt][c], eB, b[pt]);
            }
        }
        #pragma unroll
        for (int pt = 0; pt < NP; ++pt) {
            float dA = fmaf(-2.f, a[pt], z2[pt] + e2[v]);
            float dB = fmaf(-2.f, b[pt], z2[pt] + e2[v+1]);
            if (dA < best[pt]) { best[pt] = dA; bv[pt] = v; }
            if (dB < best[pt]) { best[pt] = dB; bv[pt] = v + 1; }
        }
    }
    #pragma unroll
    for (int pt = 0; pt < NP; ++pt)
        if (act[pt])
            bestk[(size_t)mm[pt] * G + g] =
                ((unsigned long long)ordf(best[pt]) << 32) |
                (unsigned long long)(unsigned int)bv[pt];
}

// Fused: group-reduce keys ([m][G], vectorized when TPP==1) -> gather +
// separable bicubic (LDS, padded) -> 3x3 conv Phi (bank-conflict-free
// transposed weights) -> f_hat/f_rest update -> emit next scale's z rows.
__global__ __launch_bounds__(256) void fuse_k(const unsigned long long* __restrict__ bestk,
                      const float* __restrict__ E,
                      const float* __restrict__ pw, const float* __restrict__ pb,
                      float* __restrict__ f_hat, float* __restrict__ f_rest,
                      float* __restrict__ z_next,
                      int pn, int G, int TPP, int kphi, int pnn) {
    __shared__ float s_buf[CC * 18 * 20];   // phase A: tmp; B+: hup padded; end: fnew
    __shared__ float s_pw[CC * 9 * 8];      // TRANSPOSED: [ci*9+tap][col]
    __shared__ int   s_idx[256];
    __shared__ float s_w[HH][4];
    __shared__ int   s_j[HH][4];
    __shared__ unsigned long long s_red[256];
    const int t   = threadIdx.x;
    const int cog = blockIdx.x;   // 0..3
    const int b   = blockIdx.y;   // 0..63
    const int P   = pn * pn;

    // ---- phase 0: reduce over G keys per point (min d, tie -> min v) ----
    if (TPP == 1) {
        if (t < P) {
            int m = b * P + t;
            const ulonglong2* kp = (const ulonglong2*)(bestk + (size_t)m * G);
            unsigned long long bk = ~0ull;
            #pragma unroll 4
            for (int gg = 0; gg < (G >> 1); ++gg) {
                ulonglong2 o = kp[gg];
                unsigned long long mn = o.x < o.y ? o.x : o.y;  // x = smaller v on tie
                if (mn < bk) bk = mn;
            }
            s_idx[t] = (int)(unsigned int)(bk & 0xffffffffull);
        }
    } else {
        int p = t / TPP, sub = t - p * TPP;
        unsigned long long bk = ~0ull;
        if (p < P) {
            const unsigned long long* kp = bestk + (size_t)(b * P + p) * G;
            for (int gg = sub; gg < G; gg += TPP) {
                unsigned long long o = kp[gg];
                if (o < bk) bk = o;
            }
        }
        s_red[t] = bk;
        __syncthreads();
        for (int s = TPP >> 1; s > 0; s >>= 1) {
            if (sub < s && p < P) {
                unsigned long long o = s_red[t + s];
                if (o < s_red[t]) s_red[t] = o;
            }
            __syncthreads();
        }
        if (t < P) s_idx[t] = (int)(unsigned int)(s_red[t * TPP] & 0xffffffffull);
    }
    if (t < HH) {
        double src = (t + 0.5) * (double)pn / 16.0 - 0.5;
        double fi = floor(src); int i0 = (int)fi; double tt = src - fi;
        #pragma unroll
        for (int k = 0; k < 4; ++k) {
            int j = i0 - 1 + k; j = j < 0 ? 0 : (j > pn - 1 ? pn - 1 : j);
            s_j[t][k] = j;
            s_w[t][k] = (float)cubicw((double)(k - 1) - tt);
        }
    }
    {
        // transposed staging: s_pw[(ci*9+tap)*8 + col] = pw[.., col, ci, tap]
        const float* src = pw + ((size_t)(kphi * CC + cog * 8)) * CC * 9;
        for (int i = t; i < 8 * CC * 9; i += 256) {
            int col = i / (CC * 9);
            int r   = i - col * (CC * 9);       // ci*9 + tap
            s_pw[r * 8 + col] = src[i];
        }
    }
    __syncthreads();

    // ---- phase A: vertical bicubic + gather: tmp[c][h][q] ----
    if (t < HH * pn) {
        int h = t / pn, q = t % pn;
        float acc[CC];
        #pragma unroll
        for (int c = 0; c < CC; ++c) acc[c] = 0.f;
        #pragma unroll
        for (int k = 0; k < 4; ++k) {
            float wv = s_w[h][k];
            int row = s_idx[s_j[h][k] * pn + q];
            const float4* er = (const float4*)(E + (size_t)row * CC);
            #pragma unroll
            for (int c4 = 0; c4 < CC / 4; ++c4) {
                float4 e4 = er[c4];
                acc[c4*4+0] = fmaf(wv, e4.x, acc[c4*4+0]);
                acc[c4*4+1] = fmaf(wv, e4.y, acc[c4*4+1]);
                acc[c4*4+2] = fmaf(wv, e4.z, acc[c4*4+2]);
                acc[c4*4+3] = fmaf(wv, e4.w, acc[c4*4+3]);
            }
        }
        #pragma unroll
        for (int c = 0; c < CC; ++c) s_buf[(c * HH + h) * pn + q] = acc[c];
    }
    __syncthreads();

    // ---- phase B: horizontal bicubic -> padded hup[c][18][20] (data [1..16][1..16]) ----
    {
        int h = t >> 4, w = t & 15;
        float acc[CC];
        #pragma unroll
        for (int c = 0; c < CC; ++c) acc[c] = 0.f;
        #pragma unroll
        for (int k = 0; k < 4; ++k) {
            float wh = s_w[w][k];
            int j = s_j[w][k];
            #pragma unroll
            for (int c = 0; c < CC; ++c)
                acc[c] = fmaf(wh, s_buf[(c * HH + h) * pn + j], acc[c]);
        }
        __syncthreads();   // all tmp reads done before aliased writes
        #pragma unroll
        for (int c = 0; c < CC; ++c) s_buf[(c * 18 + h + 1) * 20 + w + 1] = acc[c];
        if (w == 0) {
            #pragma unroll
            for (int c = 0; c < CC; ++c) s_buf[(c * 18 + h + 1) * 20] = 0.f;
        }
        if (w >= 13) {   // cols 17,18,19
            #pragma unroll
            for (int c = 0; c < CC; ++c) s_buf[(c * 18 + h + 1) * 20 + w + 4] = 0.f;
        }
        if (h == 0) {
            #pragma unroll
            for (int c = 0; c < CC; ++c) {
                s_buf[(c * 18) * 20 + w] = 0.f;
                if (w < 4) s_buf[(c * 18) * 20 + 16 + w] = 0.f;
            }
        }
        if (h == 15) {
            #pragma unroll
            for (int c = 0; c < CC; ++c) {
                s_buf[(c * 18 + 17) * 20 + w] = 0.f;
                if (w < 4) s_buf[(c * 18 + 17) * 20 + 16 + w] = 0.f;
            }
        }
    }
    __syncthreads();

    // ---- conv 3x3 (padded, branch-free; weights via transposed LDS) ----
    int col = t >> 5;                 // 0..7
    int co  = cog * 8 + col;
    int s   = t & 31;
    int h   = s >> 1;
    int w0  = (s & 1) * 8;
    float acc[8];
    float bias = pb[kphi * CC + co];
    #pragma unroll
    for (int o = 0; o < 8; ++o) acc[o] = bias;
    for (int ci = 0; ci < CC; ++ci) {
        const float* wb = &s_pw[(ci * 9) * 8 + col];
        #pragma unroll
        for (int kh = 0; kh < 3; ++kh) {
            const float4* xr = (const float4*)&s_buf[(ci * 18 + h + kh) * 20 + w0];
            float4 a0 = xr[0], a1 = xr[1], a2 = xr[2];
            float xf[12] = {a0.x, a0.y, a0.z, a0.w, a1.x, a1.y, a1.z, a1.w,
                            a2.x, a2.y, a2.z, a2.w};
            float k0 = wb[(kh*3+0)*8], k1 = wb[(kh*3+1)*8], k2 = wb[(kh*3+2)*8];
            #pragma unroll
            for (int o = 0; o < 8; ++o)
                acc[o] += xf[o] * k0 + xf[o+1] * k1 + xf[o+2] * k2;
        }
    }
    // ---- epilogue: update f_hat / f_rest ----
    size_t base = ((size_t)(b * CC + co) * HH + h) * HH + w0;
    float hf[8];
    #pragma unroll
    for (int o = 0; o < 8; ++o) {
        float hv = s_buf[(co * 18 + h + 1) * 20 + w0 + o + 1];
        hf[o] = 0.5f * hv + 0.5f * acc[o];
    }
    float4* fh = (float4*)(f_hat + base);
    float4* fr = (float4*)(f_rest + base);
    float4 v0 = fh[0], v1 = fh[1];
    v0.x += hf[0]; v0.y += hf[1]; v0.z += hf[2]; v0.w += hf[3];
    v1.x += hf[4]; v1.y += hf[5]; v1.z += hf[6]; v1.w += hf[7];
    fh[0] = v0; fh[1] = v1;
    float4 r0 = fr[0], r1 = fr[1];
    r0.x -= hf[0]; r0.y -= hf[1]; r0.z -= hf[2]; r0.w -= hf[3];
    r1.x -= hf[4]; r1.y -= hf[5]; r1.z -= hf[6]; r1.w -= hf[7];
    fr[0] = r0; fr[1] = r1;

    // ---- emit next scale's z rows for this block's 8 channels ----
    if (pnn > 0) {
        __syncthreads();   // all s_buf reads (hv/conv) complete
        float* fn = s_buf; // reuse: fnew[col][16][16]
        float* d = &fn[(col * HH + h) * HH + w0];
        d[0] = r0.x; d[1] = r0.y; d[2] = r0.z; d[3] = r0.w;
        d[4] = r1.x; d[5] = r1.y; d[6] = r1.z; d[7] = r1.w;
        __syncthreads();
        int P2 = pnn * pnn;
        for (int i = t; i < P2 * 8; i += 256) {
            int cl = i & 7, pq = i >> 3;
            int q2 = pq % pnn, p2 = pq / pnn;
            int sp = (p2 * HH) / pnn, ep = ((p2 + 1) * HH + pnn - 1) / pnn;
            int sq = (q2 * HH) / pnn, eq = ((q2 + 1) * HH + pnn - 1) / pnn;
            float wgt = 1.0f / ((float)(ep - sp) * (float)(eq - sq));
            float sum = 0.f;
            for (int h2 = sp; h2 < ep; ++h2)
                for (int w2 = sq; w2 < eq; ++w2)
                    sum += fn[(cl * HH + h2) * HH + w2];
            z_next[((size_t)(b * P2 + pq)) * CC + cog * 8 + cl] = sum * wgt;
        }
    }
}

extern "C" void kernel_launch(void* const* d_in, const int* in_sizes, int n_in,
                              void* d_out, int out_size, void* d_ws, size_t ws_size,
                              hipStream_t stream) {
    const float* f  = (const float*)d_in[0];
    const float* E  = (const float*)d_in[1];
    const float* pw = (const float*)d_in[2];
    const float* pb = (const float*)d_in[3];
    float* out = (float*)d_out;

    float* wsf    = (float*)d_ws;
    float* f_rest = wsf;
    float* e2     = wsf + (size_t)NTOT;
    unsigned long long* bestk = (unsigned long long*)(e2 + VV);  // 524288 u64 (4MB)
    float* z      = (float*)(bestk + 524288);                    // 16384*32 floats (2MB)

    // numpy _phi_select, bit-exact in IEEE double (ties at si=2,7)
    int phik[10];
    {
        double start = 1.0 / 3.0 / 4.0;
        double stop  = 1.0 - 1.0 / 3.0 / 4.0;
        double step  = (stop - start) / 3.0;
        double ticks[4];
        for (int i = 0; i < 4; ++i) ticks[i] = (double)i * step + start;
        ticks[3] = stop;
        for (int si = 0; si < 10; ++si) {
            double s = (double)si / 9.0;
            int bk = 0; double bd = fabs(ticks[0] - s);
            for (int tq = 1; tq < 4; ++tq) {
                double d2 = fabs(ticks[tq] - s);
                if (d2 < bd) { bd = d2; bk = tq; }
            }
            phik[si] = bk;
        }
    }

    static const int pns[10]  = {1, 2, 3, 4, 5, 6, 8, 10, 13, 16};
    static const int grpS[10] = {256, 128, 64, 32, 32, 16, 0, 0, 0, 0};
    // big scales: G key-rows (keys M*G <= 524288), NP points/thread
    static const int grpB[10] = {0, 0, 0, 0, 0, 0, 64, 64, 32, 32};
    static const int npB[10]  = {0, 0, 0, 0, 0, 0, 2,  2,  2,  4};

    init_k<<<(NTOT + 255) / 256, 256, 0, stream>>>(f, E, f_rest, out, e2, z);

    for (int si = 0; si < 10; ++si) {
        int pn = pns[si];
        int P = pn * pn;
        int M = BB * P;
        int G, TPP;
        if (pn <= 6) {
            int grp = grpS[si];
            G = grp * 4;
            int gsz = VV / G;
            argsmall_k<<<dim3(P, grp), 256, 0, stream>>>(z, E, e2, bestk, M, G, gsz);
        } else {
            G = grpB[si];
            int np = npB[si];
            int gsz = VV / G;
            int bx = (M + 256 * np - 1) / (256 * np);
            dim3 ag(bx, G);
            if (np == 2)
                argbig_k<2, 4><<<ag, 256, 0, stream>>>(z, E, e2, bestk, M, G, gsz);
            else
                argbig_k<4, 3><<<ag, 256, 0, stream>>>(z, E, e2, bestk, M, G, gsz);
        }
        TPP = 1;
        while (TPP * 2 * P <= 256) TPP *= 2;
        int pnn = (si < 9) ? pns[si + 1] : 0;
        fuse_k<<<dim3(4, BB), 256, 0, stream>>>(bestk, E, pw, pb,
                                                out, f_rest, z,
                                                pn, G, TPP, phik[si], pnn);
    }
}

// Round 12
// 552.225 us; speedup vs baseline: 1.0457x; 1.0457x over previous
//
#include <hip/hip_runtime.h>
#include <cmath>

// Multi-scale residual VQ, round 12.
// R11 lesson: NP=4 + launch_bounds(,3) capped VGPR at 84 -> zr spilled ->
// 108us. R10 lesson (revised): LDS-staged E was DS-bound only because the
// compiler emitted per-element ds_read_b32 (371 DS-cyc/step > 256 VALU-cyc).
// R12 argbig: NP=2 (VGPR 48, spill-free) + LDS E tile read via EXPLICIT
// float4 (ds_read_b128 broadcast: 96 DS-cyc per code < 128 VALU-cyc).
// fuse_k keeps [m][G] vectorized reduce + transposed conflict-free weights.

#define BB 64
#define CC 32
#define HH 16
#define VV 4096
#define NTOT (BB*CC*HH*HH)   // 524288

__device__ __forceinline__ double cubicw(double x) {
    x = fabs(x);
    const double a = -0.75;
    if (x <= 1.0) return ((a + 2.0) * x - (a + 3.0)) * x * x + 1.0;
    if (x < 2.0)  return (((a * x - 5.0 * a) * x + 8.0 * a) * x - 4.0 * a);
    return 0.0;
}

// monotone float->uint map: d1<d2 (finite) => ordf(d1)<ordf(d2)
__device__ __forceinline__ unsigned int ordf(float d) {
    unsigned int b = __float_as_uint(d);
    return (b & 0x80000000u) ? ~b : (b | 0x80000000u);
}

// init: f_rest=f, f_hat=0, e2 rows, and z for scale 0 (pn=1: per-(b,c) mean).
__global__ void init_k(const float* __restrict__ f, const float* __restrict__ E,
                       float* __restrict__ f_rest, float* __restrict__ f_hat,
                       float* __restrict__ e2, float* __restrict__ z) {
    int i = blockIdx.x * 256 + threadIdx.x;
    if (i < NTOT) { f_rest[i] = f[i]; f_hat[i] = 0.f; }
    if (i < VV) {
        float s = 0.f;
        #pragma unroll
        for (int c = 0; c < CC; ++c) { float e = E[i * CC + c]; s += e * e; }
        e2[i] = s;
    }
    if (i < BB * CC) {   // z0[b*32+c] = mean over 256 pixels
        const float* src = f + (size_t)i * (HH * HH);
        float s = 0.f;
        for (int j = 0; j < HH * HH; ++j) s += src[j];
        z[i] = s * (1.0f / 256.0f);
    }
}

// Small scales: grid (pn*pn, grp); block = 4 waves; each wave = same 64 points
// (one per lane), wave-specific code range (wave-uniform => scalar E loads).
// Keys stored [m][G].
__global__ __launch_bounds__(256, 4) void argsmall_k(const float* __restrict__ z,
        const float* __restrict__ E, const float* __restrict__ e2,
        unsigned long long* __restrict__ bestk, int M, int G, int gsz) {
    const int t = threadIdx.x;
    int m = blockIdx.x * 64 + (t & 63);
    int w = __builtin_amdgcn_readfirstlane(t >> 6);      // wave id, SGPR
    int wg = blockIdx.y * 4 + w;
    int v0 = wg * gsz;                                    // scalar
    float zr[CC]; float z2 = 0.f;
    const float4* zp = (const float4*)(z + (size_t)m * CC);
    #pragma unroll
    for (int c4 = 0; c4 < 8; ++c4) {
        float4 v = zp[c4];
        zr[c4*4+0] = v.x; zr[c4*4+1] = v.y; zr[c4*4+2] = v.z; zr[c4*4+3] = v.w;
        z2 += v.x*v.x + v.y*v.y + v.z*v.z + v.w*v.w;
    }
    const float* e = E + (size_t)v0 * CC;
    float best = 3.4e38f; int bv = v0;
    for (int v = v0; v < v0 + gsz; v += 2, e += 2 * CC) {
        float a0 = 0.f, a1 = 0.f, b0 = 0.f, b1 = 0.f;
        #pragma unroll
        for (int c = 0; c < CC; c += 2) {
            a0 = fmaf(zr[c],   e[c],      a0);
            a1 = fmaf(zr[c+1], e[c+1],    a1);
            b0 = fmaf(zr[c],   e[CC+c],   b0);
            b1 = fmaf(zr[c+1], e[CC+c+1], b1);
        }
        float dA = fmaf(-2.f, a0 + a1, z2 + e2[v]);
        float dB = fmaf(-2.f, b0 + b1, z2 + e2[v+1]);
        if (dA < best) { best = dA; bv = v; }
        if (dB < best) { best = dB; bv = v + 1; }
    }
    bestk[(size_t)m * G + wg] = ((unsigned long long)ordf(best) << 32) |
                                (unsigned long long)(unsigned int)bv;
}

// Large scales: 2 points/thread; E tile + e2 staged in LDS; inner loop reads
// E via explicit float4 (ds_read_b128, uniform-address broadcast). Keys [m][G].
__global__ __launch_bounds__(256, 4) void argbig_k(const float* __restrict__ z,
        const float* __restrict__ E, const float* __restrict__ e2,
        unsigned long long* __restrict__ bestk, int M, int G, int gsz) {
    __shared__ float s_e[128 * CC];   // up to 128 codes x 32 ch = 16 KB
    __shared__ float s_e2[128];
    const int T = gridDim.x * 256;
    const int g = blockIdx.y;
    const int v0 = g * gsz;
    {
        const float4* src = (const float4*)(E + (size_t)v0 * CC);
        float4* dst = (float4*)s_e;
        for (int i = threadIdx.x; i < gsz * 8; i += 256) dst[i] = src[i];
        if (threadIdx.x < gsz) s_e2[threadIdx.x] = e2[v0 + threadIdx.x];
    }
    int   mm[2];
    bool  act[2];
    float zr[2][CC];
    float z2[2];
    #pragma unroll
    for (int pt = 0; pt < 2; ++pt) {
        int m0 = blockIdx.x * 256 + threadIdx.x + pt * T;
        act[pt] = (m0 < M);
        int m = act[pt] ? m0 : M - 1;
        mm[pt] = m;
        const float4* zp = (const float4*)(z + (size_t)m * CC);
        float zz = 0.f;
        #pragma unroll
        for (int c4 = 0; c4 < 8; ++c4) {
            float4 v = zp[c4];
            zr[pt][c4*4+0] = v.x; zr[pt][c4*4+1] = v.y;
            zr[pt][c4*4+2] = v.z; zr[pt][c4*4+3] = v.w;
            zz += v.x*v.x + v.y*v.y + v.z*v.z + v.w*v.w;
        }
        z2[pt] = zz;
    }
    __syncthreads();
    float best[2]; int bv[2];
    #pragma unroll
    for (int pt = 0; pt < 2; ++pt) { best[pt] = 3.4e38f; bv[pt] = v0; }
    const float4* ev = (const float4*)s_e;
    for (int vi = 0; vi < gsz; ++vi, ev += 8) {
        float4 e0 = ev[0], e1 = ev[1], e2v = ev[2], e3 = ev[3];
        float4 e4 = ev[4], e5 = ev[5], e6v = ev[6], e7 = ev[7];
        float ef[CC] = {e0.x,e0.y,e0.z,e0.w, e1.x,e1.y,e1.z,e1.w,
                        e2v.x,e2v.y,e2v.z,e2v.w, e3.x,e3.y,e3.z,e3.w,
                        e4.x,e4.y,e4.z,e4.w, e5.x,e5.y,e5.z,e5.w,
                        e6v.x,e6v.y,e6v.z,e6v.w, e7.x,e7.y,e7.z,e7.w};
        float a0 = 0.f, a1 = 0.f, b0 = 0.f, b1 = 0.f;
        #pragma unroll
        for (int c = 0; c < CC; c += 2) {
            a0 = fmaf(zr[0][c],   ef[c],   a0);
            a1 = fmaf(zr[0][c+1], ef[c+1], a1);
            b0 = fmaf(zr[1][c],   ef[c],   b0);
            b1 = fmaf(zr[1][c+1], ef[c+1], b1);
        }
        float e2c = s_e2[vi];
        float dA = fmaf(-2.f, a0 + a1, z2[0] + e2c);
        float dB = fmaf(-2.f, b0 + b1, z2[1] + e2c);
        int v = v0 + vi;
        if (dA < best[0]) { best[0] = dA; bv[0] = v; }
        if (dB < best[1]) { best[1] = dB; bv[1] = v; }
    }
    #pragma unroll
    for (int pt = 0; pt < 2; ++pt)
        if (act[pt])
            bestk[(size_t)mm[pt] * G + g] =
                ((unsigned long long)ordf(best[pt]) << 32) |
                (unsigned long long)(unsigned int)bv[pt];
}

// Fused: group-reduce keys ([m][G], vectorized when TPP==1) -> gather +
// separable bicubic (LDS, padded) -> 3x3 conv Phi (transposed conflict-free
// weights) -> f_hat/f_rest update -> emit next scale's z rows.
__global__ __launch_bounds__(256) void fuse_k(const unsigned long long* __restrict__ bestk,
                      const float* __restrict__ E,
                      const float* __restrict__ pw, const float* __restrict__ pb,
                      float* __restrict__ f_hat, float* __restrict__ f_rest,
                      float* __restrict__ z_next,
                      int pn, int G, int TPP, int kphi, int pnn) {
    __shared__ float s_buf[CC * 18 * 20];   // phase A: tmp; B+: hup padded; end: fnew
    __shared__ float s_pw[CC * 9 * 8];      // TRANSPOSED: [ci*9+tap][col]
    __shared__ int   s_idx[256];
    __shared__ float s_w[HH][4];
    __shared__ int   s_j[HH][4];
    __shared__ unsigned long long s_red[256];
    const int t   = threadIdx.x;
    const int cog = blockIdx.x;   // 0..3
    const int b   = blockIdx.y;   // 0..63
    const int P   = pn * pn;

    // ---- phase 0: reduce over G keys per point (min d, tie -> min v) ----
    if (TPP == 1) {
        if (t < P) {
            int m = b * P + t;
            const ulonglong2* kp = (const ulonglong2*)(bestk + (size_t)m * G);
            unsigned long long bk = ~0ull;
            #pragma unroll 4
            for (int gg = 0; gg < (G >> 1); ++gg) {
                ulonglong2 o = kp[gg];
                unsigned long long mn = o.x < o.y ? o.x : o.y;
                if (mn < bk) bk = mn;
            }
            s_idx[t] = (int)(unsigned int)(bk & 0xffffffffull);
        }
    } else {
        int p = t / TPP, sub = t - p * TPP;
        unsigned long long bk = ~0ull;
        if (p < P) {
            const unsigned long long* kp = bestk + (size_t)(b * P + p) * G;
            for (int gg = sub; gg < G; gg += TPP) {
                unsigned long long o = kp[gg];
                if (o < bk) bk = o;
            }
        }
        s_red[t] = bk;
        __syncthreads();
        for (int s = TPP >> 1; s > 0; s >>= 1) {
            if (sub < s && p < P) {
                unsigned long long o = s_red[t + s];
                if (o < s_red[t]) s_red[t] = o;
            }
            __syncthreads();
        }
        if (t < P) s_idx[t] = (int)(unsigned int)(s_red[t * TPP] & 0xffffffffull);
    }
    if (t < HH) {
        double src = (t + 0.5) * (double)pn / 16.0 - 0.5;
        double fi = floor(src); int i0 = (int)fi; double tt = src - fi;
        #pragma unroll
        for (int k = 0; k < 4; ++k) {
            int j = i0 - 1 + k; j = j < 0 ? 0 : (j > pn - 1 ? pn - 1 : j);
            s_j[t][k] = j;
            s_w[t][k] = (float)cubicw((double)(k - 1) - tt);
        }
    }
    {
        // transposed staging: s_pw[(ci*9+tap)*8 + col] = pw[.., col, ci, tap]
        const float* src = pw + ((size_t)(kphi * CC + cog * 8)) * CC * 9;
        for (int i = t; i < 8 * CC * 9; i += 256) {
            int col = i / (CC * 9);
            int r   = i - col * (CC * 9);       // ci*9 + tap
            s_pw[r * 8 + col] = src[i];
        }
    }
    __syncthreads();

    // ---- phase A: vertical bicubic + gather: tmp[c][h][q] ----
    if (t < HH * pn) {
        int h = t / pn, q = t % pn;
        float acc[CC];
        #pragma unroll
        for (int c = 0; c < CC; ++c) acc[c] = 0.f;
        #pragma unroll
        for (int k = 0; k < 4; ++k) {
            float wv = s_w[h][k];
            int row = s_idx[s_j[h][k] * pn + q];
            const float4* er = (const float4*)(E + (size_t)row * CC);
            #pragma unroll
            for (int c4 = 0; c4 < CC / 4; ++c4) {
                float4 e4 = er[c4];
                acc[c4*4+0] = fmaf(wv, e4.x, acc[c4*4+0]);
                acc[c4*4+1] = fmaf(wv, e4.y, acc[c4*4+1]);
                acc[c4*4+2] = fmaf(wv, e4.z, acc[c4*4+2]);
                acc[c4*4+3] = fmaf(wv, e4.w, acc[c4*4+3]);
            }
        }
        #pragma unroll
        for (int c = 0; c < CC; ++c) s_buf[(c * HH + h) * pn + q] = acc[c];
    }
    __syncthreads();

    // ---- phase B: horizontal bicubic -> padded hup[c][18][20] ----
    {
        int h = t >> 4, w = t & 15;
        float acc[CC];
        #pragma unroll
        for (int c = 0; c < CC; ++c) acc[c] = 0.f;
        #pragma unroll
        for (int k = 0; k < 4; ++k) {
            float wh = s_w[w][k];
            int j = s_j[w][k];
            #pragma unroll
            for (int c = 0; c < CC; ++c)
                acc[c] = fmaf(wh, s_buf[(c * HH + h) * pn + j], acc[c]);
        }
        __syncthreads();   // all tmp reads done before aliased writes
        #pragma unroll
        for (int c = 0; c < CC; ++c) s_buf[(c * 18 + h + 1) * 20 + w + 1] = acc[c];
        if (w == 0) {
            #pragma unroll
            for (int c = 0; c < CC; ++c) s_buf[(c * 18 + h + 1) * 20] = 0.f;
        }
        if (w >= 13) {
            #pragma unroll
            for (int c = 0; c < CC; ++c) s_buf[(c * 18 + h + 1) * 20 + w + 4] = 0.f;
        }
        if (h == 0) {
            #pragma unroll
            for (int c = 0; c < CC; ++c) {
                s_buf[(c * 18) * 20 + w] = 0.f;
                if (w < 4) s_buf[(c * 18) * 20 + 16 + w] = 0.f;
            }
        }
        if (h == 15) {
            #pragma unroll
            for (int c = 0; c < CC; ++c) {
                s_buf[(c * 18 + 17) * 20 + w] = 0.f;
                if (w < 4) s_buf[(c * 18 + 17) * 20 + 16 + w] = 0.f;
            }
        }
    }
    __syncthreads();

    // ---- conv 3x3 (padded, branch-free; transposed weights) ----
    int col = t >> 5;                 // 0..7
    int co  = cog * 8 + col;
    int s   = t & 31;
    int h   = s >> 1;
    int w0  = (s & 1) * 8;
    float acc[8];
    float bias = pb[kphi * CC + co];
    #pragma unroll
    for (int o = 0; o < 8; ++o) acc[o] = bias;
    for (int ci = 0; ci < CC; ++ci) {
        const float* wb = &s_pw[(ci * 9) * 8 + col];
        #pragma unroll
        for (int kh = 0; kh < 3; ++kh) {
            const float4* xr = (const float4*)&s_buf[(ci * 18 + h + kh) * 20 + w0];
            float4 a0 = xr[0], a1 = xr[1], a2 = xr[2];
            float xf[12] = {a0.x, a0.y, a0.z, a0.w, a1.x, a1.y, a1.z, a1.w,
                            a2.x, a2.y, a2.z, a2.w};
            float k0 = wb[(kh*3+0)*8], k1 = wb[(kh*3+1)*8], k2 = wb[(kh*3+2)*8];
            #pragma unroll
            for (int o = 0; o < 8; ++o)
                acc[o] += xf[o] * k0 + xf[o+1] * k1 + xf[o+2] * k2;
        }
    }
    // ---- epilogue: update f_hat / f_rest ----
    size_t base = ((size_t)(b * CC + co) * HH + h) * HH + w0;
    float hf[8];
    #pragma unroll
    for (int o = 0; o < 8; ++o) {
        float hv = s_buf[(co * 18 + h + 1) * 20 + w0 + o + 1];
        hf[o] = 0.5f * hv + 0.5f * acc[o];
    }
    float4* fh = (float4*)(f_hat + base);
    float4* fr = (float4*)(f_rest + base);
    float4 v0 = fh[0], v1 = fh[1];
    v0.x += hf[0]; v0.y += hf[1]; v0.z += hf[2]; v0.w += hf[3];
    v1.x += hf[4]; v1.y += hf[5]; v1.z += hf[6]; v1.w += hf[7];
    fh[0] = v0; fh[1] = v1;
    float4 r0 = fr[0], r1 = fr[1];
    r0.x -= hf[0]; r0.y -= hf[1]; r0.z -= hf[2]; r0.w -= hf[3];
    r1.x -= hf[4]; r1.y -= hf[5]; r1.z -= hf[6]; r1.w -= hf[7];
    fr[0] = r0; fr[1] = r1;

    // ---- emit next scale's z rows for this block's 8 channels ----
    if (pnn > 0) {
        __syncthreads();   // all s_buf reads (hv/conv) complete
        float* fn = s_buf; // reuse: fnew[col][16][16]
        float* d = &fn[(col * HH + h) * HH + w0];
        d[0] = r0.x; d[1] = r0.y; d[2] = r0.z; d[3] = r0.w;
        d[4] = r1.x; d[5] = r1.y; d[6] = r1.z; d[7] = r1.w;
        __syncthreads();
        int P2 = pnn * pnn;
        for (int i = t; i < P2 * 8; i += 256) {
            int cl = i & 7, pq = i >> 3;
            int q2 = pq % pnn, p2 = pq / pnn;
            int sp = (p2 * HH) / pnn, ep = ((p2 + 1) * HH + pnn - 1) / pnn;
            int sq = (q2 * HH) / pnn, eq = ((q2 + 1) * HH + pnn - 1) / pnn;
            float wgt = 1.0f / ((float)(ep - sp) * (float)(eq - sq));
            float sum = 0.f;
            for (int h2 = sp; h2 < ep; ++h2)
                for (int w2 = sq; w2 < eq; ++w2)
                    sum += fn[(cl * HH + h2) * HH + w2];
            z_next[((size_t)(b * P2 + pq)) * CC + cog * 8 + cl] = sum * wgt;
        }
    }
}

extern "C" void kernel_launch(void* const* d_in, const int* in_sizes, int n_in,
                              void* d_out, int out_size, void* d_ws, size_t ws_size,
                              hipStream_t stream) {
    const float* f  = (const float*)d_in[0];
    const float* E  = (const float*)d_in[1];
    const float* pw = (const float*)d_in[2];
    const float* pb = (const float*)d_in[3];
    float* out = (float*)d_out;

    float* wsf    = (float*)d_ws;
    float* f_rest = wsf;
    float* e2     = wsf + (size_t)NTOT;
    unsigned long long* bestk = (unsigned long long*)(e2 + VV);  // 524288 u64 (4MB)
    float* z      = (float*)(bestk + 524288);                    // 16384*32 floats (2MB)

    // numpy _phi_select, bit-exact in IEEE double (ties at si=2,7)
    int phik[10];
    {
        double start = 1.0 / 3.0 / 4.0;
        double stop  = 1.0 - 1.0 / 3.0 / 4.0;
        double step  = (stop - start) / 3.0;
        double ticks[4];
        for (int i = 0; i < 4; ++i) ticks[i] = (double)i * step + start;
        ticks[3] = stop;
        for (int si = 0; si < 10; ++si) {
            double s = (double)si / 9.0;
            int bk = 0; double bd = fabs(ticks[0] - s);
            for (int tq = 1; tq < 4; ++tq) {
                double d2 = fabs(ticks[tq] - s);
                if (d2 < bd) { bd = d2; bk = tq; }
            }
            phik[si] = bk;
        }
    }

    static const int pns[10]  = {1, 2, 3, 4, 5, 6, 8, 10, 13, 16};
    static const int grpS[10] = {256, 128, 64, 32, 32, 16, 0, 0, 0, 0};
    // big scales: G key-rows (keys M*G <= 524288), gsz = VV/G <= 128 (LDS tile)
    static const int grpB[10] = {0, 0, 0, 0, 0, 0, 64, 64, 32, 32};

    init_k<<<(NTOT + 255) / 256, 256, 0, stream>>>(f, E, f_rest, out, e2, z);

    for (int si = 0; si < 10; ++si) {
        int pn = pns[si];
        int P = pn * pn;
        int M = BB * P;
        int G, TPP;
        if (pn <= 6) {
            int grp = grpS[si];
            G = grp * 4;
            int gsz = VV / G;
            argsmall_k<<<dim3(P, grp), 256, 0, stream>>>(z, E, e2, bestk, M, G, gsz);
        } else {
            G = grpB[si];
            int gsz = VV / G;
            int bx = (M + 511) / 512;
            dim3 ag(bx, G);
            argbig_k<<<ag, 256, 0, stream>>>(z, E, e2, bestk, M, G, gsz);
        }
        TPP = 1;
        while (TPP * 2 * P <= 256) TPP *= 2;
        int pnn = (si < 9) ? pns[si + 1] : 0;
        fuse_k<<<dim3(4, BB), 256, 0, stream>>>(bestk, E, pw, pb,
                                                out, f_rest, z,
                                                pn, G, TPP, phik[si], pnn);
    }
}